// Round 9
// baseline (1233.775 us; speedup 1.0000x reference)
//
#include <hip/hip_runtime.h>
#include <hip/hip_bf16.h>

// FEGIN: GIN graph encoder + classifier.
// gin1_fused: per-block CSR gather -> LDS bf16 hi/lo z-tile (swizzled) -> MFMA GEMM1.
// GEMM2: split-bf16 3-pass MFMA with BN-stats fused epilogue.
// CSR built per call (rank trick). Chunked pool + combine. Fused head MLP.

#define NN 100000
#define NE 1600000
#define HD 128
#define NG 128
#define NL 3
#define BN_EPS 1e-5f
#define MPAD 100096   // 782 * 128
#define PCH 8         // pool chunks per graph

typedef unsigned short u16;
typedef unsigned int u32;
typedef __attribute__((ext_vector_type(8))) short short8v;
typedef __attribute__((ext_vector_type(4))) float f32x4;

__device__ inline u16 bf16_hi(float v) {
    __hip_bfloat16 h = __float2bfloat16(v);
    return *(u16*)&h;
}
__device__ inline float bf16_f(u16 u) {
    __hip_bfloat16 h = *(__hip_bfloat16*)&u;
    return __bfloat162float(h);
}
__device__ inline void split_bf16(float v, u16* hi, u16* lo) {
    u16 h = bf16_hi(v);
    *hi = h;
    *lo = bf16_hi(v - bf16_f(h));
}

// async 16B global->LDS (wave-uniform LDS base; HW adds lane*16)
__device__ inline void gload_lds16(const void* g, void* l) {
    __builtin_amdgcn_global_load_lds(
        (const __attribute__((address_space(1))) void*)g,
        (__attribute__((address_space(3))) void*)l, 16, 0, 0);
}

// ---------------- projected embedding tables: P[17][128] ----------------
__global__ void proj_tables_kernel(const float* __restrict__ node_emb,
                                   const float* __restrict__ comp_emb,
                                   const float* __restrict__ pin_emb,
                                   const float* __restrict__ proj_w,
                                   float* __restrict__ P) {
    int c = threadIdx.x;  // 0..127
    for (int r = 0; r < 17; ++r) {
        const float* emb;
        int base;
        if (r < 5)        { emb = node_emb + r * HD;        base = 0; }
        else if (r < 11)  { emb = comp_emb + (r - 5) * HD;  base = HD; }
        else              { emb = pin_emb + (r - 11) * HD;  base = 2 * HD; }
        float acc = 0.f;
        for (int k = 0; k < HD; ++k)
            acc += emb[k] * proj_w[(size_t)(base + k) * HD + c];
        P[r * HD + c] = acc;
    }
}

// ---------------- h0 = P0[x0] + P1[x1] + P2[x2] + proj_b ----------------
__global__ __launch_bounds__(256) void embed_kernel(const int* __restrict__ x,
                                                    const float* __restrict__ P,
                                                    const float* __restrict__ proj_b,
                                                    float* __restrict__ h) {
    int i = blockIdx.x * 256 + threadIdx.x;   // one thread per (node, 4 channels)
    int n = i >> 5;
    if (n >= NN) return;
    int c4 = (i & 31) * 4;
    int i0 = x[3 * n + 0]; i0 = i0 < 0 ? 0 : (i0 > 4 ? 4 : i0);
    int i1 = x[3 * n + 1]; i1 = i1 < 0 ? 0 : (i1 > 5 ? 5 : i1);
    int i2 = x[3 * n + 2]; i2 = i2 < 0 ? 0 : (i2 > 5 ? 5 : i2);
    float4 a = *(const float4*)(P + i0 * HD + c4);
    float4 b = *(const float4*)(P + (5 + i1) * HD + c4);
    float4 c = *(const float4*)(P + (11 + i2) * HD + c4);
    float4 bb = *(const float4*)(proj_b + c4);
    float4 o;
    o.x = a.x + b.x + c.x + bb.x;
    o.y = a.y + b.y + c.y + bb.y;
    o.z = a.z + b.z + c.z + bb.z;
    o.w = a.w + b.w + c.w + bb.w;
    *(float4*)(h + (size_t)n * HD + c4) = o;
}

// ---------------- CSR build (rank trick: atomics only in hist) ----------------
__global__ void hist_kernel(const int* __restrict__ dst, int* __restrict__ deg,
                            int* __restrict__ rank) {
    int e = blockIdx.x * 256 + threadIdx.x;
    if (e < NE) rank[e] = atomicAdd(&deg[dst[e]], 1);
}

__global__ __launch_bounds__(256) void scan1_kernel(const int* __restrict__ deg,
                                                    int* __restrict__ rowstart,
                                                    int* __restrict__ partials) {
    __shared__ int arr[256];
    int blk = blockIdx.x, t = threadIdx.x;
    int base = blk * 2048 + t * 8;
    int v[8];
    int s = 0;
#pragma unroll
    for (int j = 0; j < 8; ++j) {
        int idx = base + j;
        int d = (idx < NN) ? deg[idx] : 0;
        v[j] = s;
        s += d;
    }
    int own = s;
    arr[t] = s;
    __syncthreads();
    for (int off = 1; off < 256; off <<= 1) {
        int add = (t >= off) ? arr[t - off] : 0;
        __syncthreads();
        arr[t] += add;
        __syncthreads();
    }
    int excl = arr[t] - own;
#pragma unroll
    for (int j = 0; j < 8; ++j) {
        int idx = base + j;
        if (idx < NN) rowstart[idx] = excl + v[j];
    }
    if (t == 255) partials[blk] = arr[255];
}

__global__ void scan2_kernel(int* __restrict__ partials, int* __restrict__ rowstart, int nblk) {
    if (threadIdx.x == 0) {
        int run = 0;
        for (int b = 0; b < nblk; ++b) {
            int p = partials[b];
            partials[b] = run;
            run += p;
        }
        rowstart[NN] = run;
    }
}

__global__ void scan3_kernel(int* __restrict__ rowstart, const int* __restrict__ partials) {
    int i = blockIdx.x * 256 + threadIdx.x;
    if (i < NN) rowstart[i] += partials[i >> 11];
}

__global__ void fill_kernel(const int* __restrict__ src, const int* __restrict__ dst,
                            const int* __restrict__ rowstart, const int* __restrict__ rank,
                            int* __restrict__ csr_src) {
    int e = blockIdx.x * 256 + threadIdx.x;
    if (e < NE) csr_src[rowstart[dst[e]] + rank[e]] = src[e];
}

// -------- split + transpose GIN weights: w1t[l][n][k], w2t[l][n][k] --------
__global__ __launch_bounds__(256) void prep_weights_kernel(const float* __restrict__ gw1,
                                                           const float* __restrict__ gw2,
                                                           u16* __restrict__ w1hi, u16* __restrict__ w1lo,
                                                           u16* __restrict__ w2hi, u16* __restrict__ w2lo) {
    int i = blockIdx.x * 256 + threadIdx.x;
    if (i >= NL * 32768) return;
    int l = i / 32768, rem = i % 32768;
    // w1t[l][n][k] = gw1[l][k][n], n<256, k<128
    int n1 = rem >> 7, k1 = rem & 127;
    split_bf16(gw1[(size_t)l * 32768 + (size_t)k1 * 256 + n1], &w1hi[i], &w1lo[i]);
    // w2t[l][n][k] = gw2[l][k][n], n<128, k<256
    int n2 = rem >> 8, k2 = rem & 255;
    split_bf16(gw2[(size_t)l * 32768 + (size_t)k2 * 128 + n2], &w2hi[i], &w2lo[i]);
}

// ======== fused gather + GEMM1: z = h + sum_edges h[src]; z1 = relu(z@W1 + b1) ========
// Block: 128 rows x all 256 cols, 512 threads (8 waves).
// Phase 1: 8 waves x 16 rows CSR-gather into LDS z-tile, pre-split bf16 hi/lo,
//   XOR-swizzled 16B chunks: chunk' = chunk ^ (row&7)  (write 4 lanes/chunk,
//   read 2 lanes/chunk -> both bank-conflict-free).
// Phase 2: per-wave 64x64 output (wm=wv>>2, wn=wv&3), K=128 in 4 steps,
//   A-frags from LDS (1x ds_read_b128), B-frags from global (L2-hot), 3-pass split MFMA.
__global__ __launch_bounds__(512, 4) void gin1_fused(const float* __restrict__ h,
                                                     const int* __restrict__ rowstart,
                                                     const int* __restrict__ csr_src,
                                                     const u16* __restrict__ Bhi,
                                                     const u16* __restrict__ Blo,
                                                     const float* __restrict__ bias,
                                                     u16* __restrict__ Ohi,
                                                     u16* __restrict__ Olo) {
    __shared__ __align__(16) u16 zh[16384];  // 32 KiB: [128 rows][128 ch] bf16 hi
    __shared__ __align__(16) u16 zl[16384];  // 32 KiB: lo plane
    const int t = threadIdx.x;
    const int wv = t >> 6, lane = t & 63;
    const int m0 = blockIdx.x * 128;

    // ---- phase 1: gather ----
    const float2* hp = (const float2*)h;
    for (int i = 0; i < 16; ++i) {
        int lr = wv * 16 + i;               // tile-local row
        int gr = m0 + lr;                   // global row
        int hrow = gr < NN ? gr : NN - 1;
        float2 acc = hp[(size_t)hrow * 64 + lane];
        int beg = 0, end = 0;
        if (gr < NN) {
            beg = __builtin_amdgcn_readfirstlane(rowstart[gr]);
            end = __builtin_amdgcn_readfirstlane(rowstart[gr + 1]);
        }
        for (int base = beg; base < end; base += 64) {
            int cnt = end - base;
            if (cnt > 64) cnt = 64;
            int idx = (lane < cnt) ? csr_src[base + lane] : 0;  // coalesced index load
            int j = 0;
            for (; j + 8 <= cnt; j += 8) {
                int s0 = __shfl(idx, j);
                int s1 = __shfl(idx, j + 1);
                int s2 = __shfl(idx, j + 2);
                int s3 = __shfl(idx, j + 3);
                int s4 = __shfl(idx, j + 4);
                int s5 = __shfl(idx, j + 5);
                int s6 = __shfl(idx, j + 6);
                int s7 = __shfl(idx, j + 7);
                float2 v0 = hp[(size_t)s0 * 64 + lane];
                float2 v1 = hp[(size_t)s1 * 64 + lane];
                float2 v2 = hp[(size_t)s2 * 64 + lane];
                float2 v3 = hp[(size_t)s3 * 64 + lane];
                float2 v4 = hp[(size_t)s4 * 64 + lane];
                float2 v5 = hp[(size_t)s5 * 64 + lane];
                float2 v6 = hp[(size_t)s6 * 64 + lane];
                float2 v7 = hp[(size_t)s7 * 64 + lane];
                acc.x += v0.x; acc.y += v0.y;
                acc.x += v1.x; acc.y += v1.y;
                acc.x += v2.x; acc.y += v2.y;
                acc.x += v3.x; acc.y += v3.y;
                acc.x += v4.x; acc.y += v4.y;
                acc.x += v5.x; acc.y += v5.y;
                acc.x += v6.x; acc.y += v6.y;
                acc.x += v7.x; acc.y += v7.y;
            }
            for (; j < cnt; ++j) {
                int s = __shfl(idx, j);
                float2 v = hp[(size_t)s * 64 + lane];
                acc.x += v.x;
                acc.y += v.y;
            }
        }
        // split + swizzled LDS write (channels 2*lane, 2*lane+1)
        u16 h0, l0, h1, l1;
        split_bf16(acc.x, &h0, &l0);
        split_bf16(acc.y, &h1, &l1);
        int addr = lr * 128 + (((lane >> 2) ^ (lr & 7)) << 3) + (lane & 3) * 2;  // u16 units
        *(u32*)(zh + addr) = (u32)h0 | ((u32)h1 << 16);
        *(u32*)(zl + addr) = (u32)l0 | ((u32)l1 << 16);
    }
    __syncthreads();

    // ---- phase 2: MFMA ----
    const int wm = wv >> 2, wn = wv & 3;
    const int l15 = lane & 15, l4 = lane >> 4;
    f32x4 acc[4][4];
#pragma unroll
    for (int m = 0; m < 4; ++m)
#pragma unroll
        for (int n = 0; n < 4; ++n)
            acc[m][n] = (f32x4){0.f, 0.f, 0.f, 0.f};

#pragma unroll
    for (int ks = 0; ks < 4; ++ks) {
        // A-frags from LDS (swizzled)
        short8v ah[4], al[4];
#pragma unroll
        for (int m = 0; m < 4; ++m) {
            int rA = wm * 64 + m * 16 + l15;
            int au = rA * 128 + (((ks * 4 + l4) ^ (rA & 7)) << 3);
            ah[m] = *(const short8v*)(zh + au);
            al[m] = *(const short8v*)(zl + au);
        }
        // B-frags from global, pipelined over n
        int col0 = wn * 64 + l15;
        const u16* bph = Bhi + (size_t)col0 * 128 + ks * 32 + l4 * 8;
        const u16* bpl = Blo + (size_t)col0 * 128 + ks * 32 + l4 * 8;
        short8v bh_cur = *(const short8v*)bph;
        short8v bl_cur = *(const short8v*)bpl;
#pragma unroll
        for (int n = 0; n < 4; ++n) {
            short8v bh_nxt, bl_nxt;
            if (n < 3) {
                bh_nxt = *(const short8v*)(bph + (n + 1) * 16 * 128);
                bl_nxt = *(const short8v*)(bpl + (n + 1) * 16 * 128);
            }
#pragma unroll
            for (int m = 0; m < 4; ++m) {
                acc[m][n] = __builtin_amdgcn_mfma_f32_16x16x32_bf16(ah[m], bh_cur, acc[m][n], 0, 0, 0);
                acc[m][n] = __builtin_amdgcn_mfma_f32_16x16x32_bf16(ah[m], bl_cur, acc[m][n], 0, 0, 0);
                acc[m][n] = __builtin_amdgcn_mfma_f32_16x16x32_bf16(al[m], bh_cur, acc[m][n], 0, 0, 0);
            }
            if (n < 3) { bh_cur = bh_nxt; bl_cur = bl_nxt; }
        }
    }

    // ---- epilogue: bias + relu + split, store z1 planes ----
#pragma unroll
    for (int n = 0; n < 4; ++n) {
        int gcol = wn * 64 + n * 16 + l15;
        float bv = bias[gcol];
#pragma unroll
        for (int m = 0; m < 4; ++m) {
#pragma unroll
            for (int r = 0; r < 4; ++r) {
                int grow = m0 + wm * 64 + m * 16 + l4 * 4 + r;
                float v = fmaxf(acc[m][n][r] + bv, 0.f);
                u16 hi, lo;
                split_bf16(v, &hi, &lo);
                Ohi[(size_t)grow * 256 + gcol] = hi;
                Olo[(size_t)grow * 256 + gcol] = lo;
            }
        }
    }
}

// -------- split-bf16 MFMA GEMM2: C[M,128] = A[M,256] @ Bt[128,256]^T + bias --------
// (structure as before; STATS: per-column sum/sumsq of output rows < NN)
template <int K, int N, int RELU, int SPLIT, int STATS>
__global__ __launch_bounds__(256) void gemm_sp(const u16* __restrict__ Ahi, const u16* __restrict__ Alo,
                                               const u16* __restrict__ Bhi, const u16* __restrict__ Blo,
                                               const float* __restrict__ bias,
                                               u16* __restrict__ Ohi, u16* __restrict__ Olo,
                                               float* __restrict__ Of,
                                               float* __restrict__ sums) {
    __shared__ __align__(16) u16 lds[16384];  // 32 KiB: 4 planes x [128][32]
    const int t = threadIdx.x;
    const int wv = t >> 6, lane = t & 63;
    const int l15 = lane & 15, l4 = lane >> 4;
    const int m0 = blockIdx.x * 128, n0 = blockIdx.y * 128;
    const int wm = wv >> 1, wn = wv & 1;
    const int lrow = lane >> 2, lchunk = lane & 3;

    f32x4 acc[4][4];
#pragma unroll
    for (int m = 0; m < 4; ++m)
#pragma unroll
        for (int n = 0; n < 4; ++n)
            acc[m][n] = (f32x4){0.f, 0.f, 0.f, 0.f};

    for (int kb = 0; kb < K; kb += 32) {
        // ---- stage 4 planes, each wave fills 16-row slices (1KB per issue) ----
#pragma unroll
        for (int p = 0; p < 4; ++p) {
            const u16* plane = (p == 0) ? Ahi : (p == 1) ? Alo : (p == 2) ? Bhi : Blo;
            const int rbase = (p < 2) ? m0 : n0;
#pragma unroll
            for (int hh = 0; hh < 2; ++hh) {
                int row = hh * 64 + wv * 16 + lrow;          // tile-local row 0..127
                int cg = lchunk ^ ((row >> 1) & 3);          // inverse-swizzled src chunk
                const u16* src = plane + (size_t)(rbase + row) * K + kb + cg * 8;
                u16* dst = lds + p * 4096 + hh * 2048 + wv * 512;  // wave-uniform base
                gload_lds16(src, dst);
            }
        }
        __syncthreads();

        // ---- fragments: lane reads 8 contiguous k at swizzled chunk ----
        short8v ah[4], al[4], bh[4], bl[4];
#pragma unroll
        for (int i = 0; i < 4; ++i) {
            int rowA = wm * 64 + i * 16 + l15;
            int pca = l4 ^ ((rowA >> 1) & 3);
            ah[i] = *(const short8v*)(lds + 0    + rowA * 32 + pca * 8);
            al[i] = *(const short8v*)(lds + 4096 + rowA * 32 + pca * 8);
            int rowB = wn * 64 + i * 16 + l15;
            int pcb = l4 ^ ((rowB >> 1) & 3);
            bh[i] = *(const short8v*)(lds + 8192  + rowB * 32 + pcb * 8);
            bl[i] = *(const short8v*)(lds + 12288 + rowB * 32 + pcb * 8);
        }
        // ---- 3-pass split product (fp32 accumulate) ----
#pragma unroll
        for (int m = 0; m < 4; ++m)
#pragma unroll
            for (int n = 0; n < 4; ++n) {
                acc[m][n] = __builtin_amdgcn_mfma_f32_16x16x32_bf16(ah[m], bh[n], acc[m][n], 0, 0, 0);
                acc[m][n] = __builtin_amdgcn_mfma_f32_16x16x32_bf16(ah[m], bl[n], acc[m][n], 0, 0, 0);
                acc[m][n] = __builtin_amdgcn_mfma_f32_16x16x32_bf16(al[m], bh[n], acc[m][n], 0, 0, 0);
            }
        __syncthreads();
    }

    // ---- epilogue: C/D mapping col = lane&15, row = (lane>>4)*4 + r ----
#pragma unroll
    for (int n = 0; n < 4; ++n) {
        int gcol = n0 + wn * 64 + n * 16 + l15;
        float bv = bias[gcol];
        float s = 0.f, q = 0.f;
#pragma unroll
        for (int m = 0; m < 4; ++m) {
#pragma unroll
            for (int r = 0; r < 4; ++r) {
                int grow = m0 + wm * 64 + m * 16 + l4 * 4 + r;
                float v = acc[m][n][r] + bv;
                if (RELU) v = fmaxf(v, 0.f);
                if (SPLIT) {
                    u16 hi, lo;
                    split_bf16(v, &hi, &lo);
                    Ohi[(size_t)grow * N + gcol] = hi;
                    Olo[(size_t)grow * N + gcol] = lo;
                } else {
                    Of[(size_t)grow * N + gcol] = v;
                }
                if (STATS) {
                    if (grow < NN) { s += v; q += v * v; }
                }
            }
        }
        if (STATS) {
            // reduce across the 4 row-groups (lanes l4=0..3 share gcol)
            s += __shfl_xor(s, 16); s += __shfl_xor(s, 32);
            q += __shfl_xor(q, 16); q += __shfl_xor(q, 32);
            if (l4 == 0) {
                atomicAdd(&sums[gcol], s);
                atomicAdd(&sums[128 + gcol], q);
            }
        }
    }
}

__global__ void bn_finalize_kernel(const float* __restrict__ sums,
                                   const float* __restrict__ gamma,
                                   const float* __restrict__ beta,
                                   float* __restrict__ scale, float* __restrict__ shift) {
    int c = threadIdx.x;  // 128
    float mean = sums[c] / (float)NN;
    float var = sums[128 + c] / (float)NN - mean * mean;
    float rstd = rsqrtf(fmaxf(var, 0.f) + BN_EPS);
    float sc = rstd * gamma[c];
    scale[c] = sc;
    shift[c] = beta[c] - mean * sc;
}

// -------- h = relu(z2*scale+shift) (+ h residual), in-place on h --------
__global__ __launch_bounds__(256) void bn_apply_kernel(const float* __restrict__ z2,
                                                       const float* __restrict__ scale,
                                                       const float* __restrict__ shift,
                                                       float* __restrict__ h, int use_res) {
    int i = blockIdx.x * 256 + threadIdx.x;  // per float4
    if (i >= NN * 32) return;
    int c4 = (i & 31) * 4;
    float4 v = ((const float4*)z2)[i];
    float4 sc = *(const float4*)(scale + c4);
    float4 sh = *(const float4*)(shift + c4);
    float4 o;
    o.x = fmaxf(v.x * sc.x + sh.x, 0.f);
    o.y = fmaxf(v.y * sc.y + sh.y, 0.f);
    o.z = fmaxf(v.z * sc.z + sh.z, 0.f);
    o.w = fmaxf(v.w * sc.w + sh.w, 0.f);
    if (use_res) {
        float4 r = ((float4*)h)[i];
        o.x += r.x; o.y += r.y; o.z += r.z; o.w += r.w;
    }
    ((float4*)h)[i] = o;
}

// ---------------- pooling: chunked partials + combine (batch sorted) ----------------
__global__ __launch_bounds__(256) void pool_part_kernel(const float* __restrict__ h,
                                                        const int* __restrict__ batch,
                                                        float* __restrict__ psum,
                                                        float* __restrict__ pmax) {
    __shared__ int bounds[2];
    __shared__ float redS[256], redM[256];
    int g = blockIdx.x, chunk = blockIdx.y, t = threadIdx.x;
    if (t < 2) {
        int target = g + t, lo = 0, hi = NN;
        while (lo < hi) {
            int mid = (lo + hi) >> 1;
            if (batch[mid] < target) lo = mid + 1;
            else hi = mid;
        }
        bounds[t] = lo;
    }
    __syncthreads();
    int lo = bounds[0], hi = bounds[1], len = hi - lo;
    int c0 = lo + (len * chunk) / PCH;
    int c1 = lo + (len * (chunk + 1)) / PCH;
    int c = t & 127, half = t >> 7;
    float s = 0.f, m = -3.4e38f;
    for (int r = c0 + half; r < c1; r += 2) {
        float v = h[(size_t)r * HD + c];
        s += v;
        m = fmaxf(m, v);
    }
    redS[t] = s;
    redM[t] = m;
    __syncthreads();
    if (t < 128) {
        psum[((size_t)g * PCH + chunk) * HD + t] = redS[t] + redS[t + 128];
        pmax[((size_t)g * PCH + chunk) * HD + t] = fmaxf(redM[t], redM[t + 128]);
    }
}

__global__ __launch_bounds__(128) void pool_combine_kernel(const float* __restrict__ psum,
                                                           const float* __restrict__ pmax,
                                                           const int* __restrict__ batch,
                                                           float* __restrict__ emb) {
    __shared__ int bounds[2];
    int g = blockIdx.x, t = threadIdx.x;
    if (t < 2) {
        int target = g + t, lo = 0, hi = NN;
        while (lo < hi) {
            int mid = (lo + hi) >> 1;
            if (batch[mid] < target) lo = mid + 1;
            else hi = mid;
        }
        bounds[t] = lo;
    }
    __syncthreads();
    int len = bounds[1] - bounds[0];
    float s = 0.f, m = -3.4e38f;
#pragma unroll
    for (int ch = 0; ch < PCH; ++ch) {
        s += psum[((size_t)g * PCH + ch) * HD + t];
        m = fmaxf(m, pmax[((size_t)g * PCH + ch) * HD + t]);
    }
    float mean;
    if (len > 0) {
        mean = s / (float)len;
    } else {
        mean = 0.f; m = 0.f; s = 0.f;
    }
    emb[g * 384 + t] = mean;
    emb[g * 384 + 128 + t] = m;
    emb[g * 384 + 256 + t] = s;
}

// ---------------- head MLP: one block per graph ----------------
__global__ __launch_bounds__(256) void head_kernel(const float* __restrict__ emb,
                                                   const float* __restrict__ w1, const float* __restrict__ b1,
                                                   const float* __restrict__ w2, const float* __restrict__ b2,
                                                   const float* __restrict__ cw, const float* __restrict__ cb,
                                                   float* __restrict__ out) {
    __shared__ float e[384], f1[256], f2[128];
    int g = blockIdx.x, t = threadIdx.x;
    e[t] = emb[g * 384 + t];
    if (t < 128) e[256 + t] = emb[g * 384 + 256 + t];
    __syncthreads();
    float acc = b1[t];
    for (int k = 0; k < 384; ++k) acc += e[k] * w1[(size_t)k * 256 + t];
    f1[t] = fmaxf(acc, 0.f);
    __syncthreads();
    if (t < 128) {
        float a2 = b2[t];
        for (int k = 0; k < 256; ++k) a2 += f1[k] * w2[k * 128 + t];
        f2[t] = fmaxf(a2, 0.f);
    }
    __syncthreads();
    if (t < 4) {
        float a3 = cb[t];
        for (int k = 0; k < 128; ++k) a3 += f2[k] * cw[k * 4 + t];
        out[g * 4 + t] = a3;
    }
}

// ---------------- launch ----------------
extern "C" void kernel_launch(void* const* d_in, const int* in_sizes, int n_in,
                              void* d_out, int out_size, void* d_ws, size_t ws_size,
                              hipStream_t stream) {
    const int* x = (const int*)d_in[0];
    const int* edge = (const int*)d_in[1];
    const int* batch = (const int*)d_in[2];
    const float* node_emb = (const float*)d_in[3];
    const float* comp_emb = (const float*)d_in[4];
    const float* pin_emb = (const float*)d_in[5];
    const float* proj_w = (const float*)d_in[6];
    const float* proj_b = (const float*)d_in[7];
    const float* gin_w1 = (const float*)d_in[8];
    const float* gin_b1 = (const float*)d_in[9];
    const float* gin_w2 = (const float*)d_in[10];
    const float* gin_b2 = (const float*)d_in[11];
    const float* bn_gamma = (const float*)d_in[12];
    const float* bn_beta = (const float*)d_in[13];
    const float* fus_w1 = (const float*)d_in[14];
    const float* fus_b1 = (const float*)d_in[15];
    const float* fus_w2 = (const float*)d_in[16];
    const float* fus_b2 = (const float*)d_in[17];
    const float* cls_w = (const float*)d_in[18];
    const float* cls_b = (const float*)d_in[19];

    const int* esrc = edge;
    const int* edst = edge + NE;

    char* ws = (char*)d_ws;
    size_t off = 0;
    auto alloc = [&](size_t bytes) -> void* {
        void* p = ws + off;
        off = (off + bytes + 255) & ~(size_t)255;
        return p;
    };
    float* h = (float*)alloc((size_t)NN * HD * 4);               // node features (fp32)
    float* z2 = (float*)alloc((size_t)MPAD * HD * 4);            // GEMM2 output (fp32)
    u16* z1_hi = (u16*)alloc((size_t)MPAD * 256 * 2);
    u16* z1_lo = (u16*)alloc((size_t)MPAD * 256 * 2);
    u16* w1hi = (u16*)alloc((size_t)NL * 32768 * 2);
    u16* w1lo = (u16*)alloc((size_t)NL * 32768 * 2);
    u16* w2hi = (u16*)alloc((size_t)NL * 32768 * 2);
    u16* w2lo = (u16*)alloc((size_t)NL * 32768 * 2);
    float* P = (float*)alloc(17 * HD * 4);
    float* sums = (float*)alloc(256 * 4);
    float* scale = (float*)alloc(HD * 4);
    float* shift = (float*)alloc(HD * 4);
    float* emb = (float*)alloc((size_t)NG * 384 * 4);
    float* psum = (float*)alloc((size_t)NG * PCH * HD * 4);
    float* pmax = (float*)alloc((size_t)NG * PCH * HD * 4);
    int* deg = (int*)alloc((size_t)NN * 4);
    int* rowstart = (int*)alloc((size_t)(NN + 1) * 4);
    int* rank = (int*)alloc((size_t)NE * 4);
    int* csr_src = (int*)alloc((size_t)NE * 4);
    int* partials = (int*)alloc(64 * 4);

    // embedding + projection + weight prep
    proj_tables_kernel<<<1, 128, 0, stream>>>(node_emb, comp_emb, pin_emb, proj_w, P);
    embed_kernel<<<(NN * 32 + 255) / 256, 256, 0, stream>>>(x, P, proj_b, h);
    prep_weights_kernel<<<(NL * 32768 + 255) / 256, 256, 0, stream>>>(gin_w1, gin_w2,
                                                                      w1hi, w1lo, w2hi, w2lo);

    // CSR build (once per call; atomics only in hist, ranks recorded)
    hipMemsetAsync(deg, 0, (size_t)NN * 4, stream);
    hist_kernel<<<(NE + 255) / 256, 256, 0, stream>>>(edst, deg, rank);
    int nblk = (NN + 2047) / 2048;  // 49
    scan1_kernel<<<nblk, 256, 0, stream>>>(deg, rowstart, partials);
    scan2_kernel<<<1, 64, 0, stream>>>(partials, rowstart, nblk);
    scan3_kernel<<<(NN + 255) / 256, 256, 0, stream>>>(rowstart, partials);
    fill_kernel<<<(NE + 255) / 256, 256, 0, stream>>>(esrc, edst, rowstart, rank, csr_src);

    const int gm = MPAD / 128;  // 782
    for (int l = 0; l < NL; ++l) {
        gin1_fused<<<gm, 512, 0, stream>>>(h, rowstart, csr_src,
                                           w1hi + (size_t)l * 32768, w1lo + (size_t)l * 32768,
                                           gin_b1 + (size_t)l * 256, z1_hi, z1_lo);
        hipMemsetAsync(sums, 0, 256 * 4, stream);
        gemm_sp<256, 128, 0, 0, 1><<<dim3(gm, 1), 256, 0, stream>>>(
            z1_hi, z1_lo, w2hi + (size_t)l * 32768, w2lo + (size_t)l * 32768,
            gin_b2 + (size_t)l * HD, nullptr, nullptr, z2, sums);
        bn_finalize_kernel<<<1, 128, 0, stream>>>(sums, bn_gamma + l * HD, bn_beta + l * HD, scale, shift);
        bn_apply_kernel<<<(NN * 32 + 255) / 256, 256, 0, stream>>>(z2, scale, shift, h, l > 0 ? 1 : 0);
    }

    pool_part_kernel<<<dim3(NG, PCH), 256, 0, stream>>>(h, batch, psum, pmax);
    pool_combine_kernel<<<NG, 128, 0, stream>>>(psum, pmax, batch, emb);
    head_kernel<<<NG, 256, 0, stream>>>(emb, fus_w1, fus_b1, fus_w2, fus_b2, cls_w, cls_b,
                                        (float*)d_out);
}

// Round 10
// 1037.988 us; speedup vs baseline: 1.1886x; 1.1886x over previous
//
#include <hip/hip_runtime.h>
#include <hip/hip_bf16.h>

// FEGIN: GIN graph encoder + classifier.
// segsum standalone (high-occupancy CSR gather). gin_mlp: fused GEMM1+GEMM2 per
// 64-row tile, z1 kept in LDS (never hits HBM), split-bf16 3-pass MFMA, BN-stats
// fused epilogue. CSR rank-trick build. Chunked pool + combine. Fused head MLP.

#define NN 100000
#define NE 1600000
#define HD 128
#define NG 128
#define NL 3
#define BN_EPS 1e-5f
#define MPAD 100096   // 1564 * 64
#define PCH 8         // pool chunks per graph

typedef unsigned short u16;
typedef unsigned int u32;
typedef __attribute__((ext_vector_type(8))) short short8v;
typedef __attribute__((ext_vector_type(4))) float f32x4;

__device__ inline u16 bf16_hi(float v) {
    __hip_bfloat16 h = __float2bfloat16(v);
    return *(u16*)&h;
}
__device__ inline float bf16_f(u16 u) {
    __hip_bfloat16 h = *(__hip_bfloat16*)&u;
    return __bfloat162float(h);
}
__device__ inline void split_bf16(float v, u16* hi, u16* lo) {
    u16 h = bf16_hi(v);
    *hi = h;
    *lo = bf16_hi(v - bf16_f(h));
}

// async 16B global->LDS (wave-uniform LDS base; HW adds lane*16)
__device__ inline void gload_lds16(const void* g, void* l) {
    __builtin_amdgcn_global_load_lds(
        (const __attribute__((address_space(1))) void*)g,
        (__attribute__((address_space(3))) void*)l, 16, 0, 0);
}

// ---------------- projected embedding tables: P[17][128] ----------------
__global__ void proj_tables_kernel(const float* __restrict__ node_emb,
                                   const float* __restrict__ comp_emb,
                                   const float* __restrict__ pin_emb,
                                   const float* __restrict__ proj_w,
                                   float* __restrict__ P) {
    int c = threadIdx.x;  // 0..127
    for (int r = 0; r < 17; ++r) {
        const float* emb;
        int base;
        if (r < 5)        { emb = node_emb + r * HD;        base = 0; }
        else if (r < 11)  { emb = comp_emb + (r - 5) * HD;  base = HD; }
        else              { emb = pin_emb + (r - 11) * HD;  base = 2 * HD; }
        float acc = 0.f;
        for (int k = 0; k < HD; ++k)
            acc += emb[k] * proj_w[(size_t)(base + k) * HD + c];
        P[r * HD + c] = acc;
    }
}

// ---------------- h0 = P0[x0] + P1[x1] + P2[x2] + proj_b ----------------
__global__ __launch_bounds__(256) void embed_kernel(const int* __restrict__ x,
                                                    const float* __restrict__ P,
                                                    const float* __restrict__ proj_b,
                                                    float* __restrict__ h) {
    int i = blockIdx.x * 256 + threadIdx.x;
    int n = i >> 5;
    if (n >= NN) return;
    int c4 = (i & 31) * 4;
    int i0 = x[3 * n + 0]; i0 = i0 < 0 ? 0 : (i0 > 4 ? 4 : i0);
    int i1 = x[3 * n + 1]; i1 = i1 < 0 ? 0 : (i1 > 5 ? 5 : i1);
    int i2 = x[3 * n + 2]; i2 = i2 < 0 ? 0 : (i2 > 5 ? 5 : i2);
    float4 a = *(const float4*)(P + i0 * HD + c4);
    float4 b = *(const float4*)(P + (5 + i1) * HD + c4);
    float4 c = *(const float4*)(P + (11 + i2) * HD + c4);
    float4 bb = *(const float4*)(proj_b + c4);
    float4 o;
    o.x = a.x + b.x + c.x + bb.x;
    o.y = a.y + b.y + c.y + bb.y;
    o.z = a.z + b.z + c.z + bb.z;
    o.w = a.w + b.w + c.w + bb.w;
    *(float4*)(h + (size_t)n * HD + c4) = o;
}

// ---------------- CSR build (rank trick: atomics only in hist) ----------------
__global__ void hist_kernel(const int* __restrict__ dst, int* __restrict__ deg,
                            int* __restrict__ rank) {
    int e = blockIdx.x * 256 + threadIdx.x;
    if (e < NE) rank[e] = atomicAdd(&deg[dst[e]], 1);
}

__global__ __launch_bounds__(256) void scan1_kernel(const int* __restrict__ deg,
                                                    int* __restrict__ rowstart,
                                                    int* __restrict__ partials) {
    __shared__ int arr[256];
    int blk = blockIdx.x, t = threadIdx.x;
    int base = blk * 2048 + t * 8;
    int v[8];
    int s = 0;
#pragma unroll
    for (int j = 0; j < 8; ++j) {
        int idx = base + j;
        int d = (idx < NN) ? deg[idx] : 0;
        v[j] = s;
        s += d;
    }
    int own = s;
    arr[t] = s;
    __syncthreads();
    for (int off = 1; off < 256; off <<= 1) {
        int add = (t >= off) ? arr[t - off] : 0;
        __syncthreads();
        arr[t] += add;
        __syncthreads();
    }
    int excl = arr[t] - own;
#pragma unroll
    for (int j = 0; j < 8; ++j) {
        int idx = base + j;
        if (idx < NN) rowstart[idx] = excl + v[j];
    }
    if (t == 255) partials[blk] = arr[255];
}

__global__ void scan2_kernel(int* __restrict__ partials, int* __restrict__ rowstart, int nblk) {
    if (threadIdx.x == 0) {
        int run = 0;
        for (int b = 0; b < nblk; ++b) {
            int p = partials[b];
            partials[b] = run;
            run += p;
        }
        rowstart[NN] = run;
    }
}

__global__ void scan3_kernel(int* __restrict__ rowstart, const int* __restrict__ partials) {
    int i = blockIdx.x * 256 + threadIdx.x;
    if (i < NN) rowstart[i] += partials[i >> 11];
}

__global__ void fill_kernel(const int* __restrict__ src, const int* __restrict__ dst,
                            const int* __restrict__ rowstart, const int* __restrict__ rank,
                            int* __restrict__ csr_src) {
    int e = blockIdx.x * 256 + threadIdx.x;
    if (e < NE) csr_src[rowstart[dst[e]] + rank[e]] = src[e];
}

// -------- z = h + sum_{in-edges} h[src]; emit bf16 hi/lo planes --------
// one wave per node; 64 edge indices loaded coalesced, rows gathered 8-deep.
__global__ __launch_bounds__(256) void segsum_kernel(const float* __restrict__ h,
                                                     const int* __restrict__ rowstart,
                                                     const int* __restrict__ csr_src,
                                                     u16* __restrict__ zhi,
                                                     u16* __restrict__ zlo) {
    int wid = (blockIdx.x * 256 + threadIdx.x) >> 6;
    int lane = threadIdx.x & 63;
    if (wid >= NN) return;
    int beg = __builtin_amdgcn_readfirstlane(rowstart[wid]);
    int end = __builtin_amdgcn_readfirstlane(rowstart[wid + 1]);
    const float2* hp = (const float2*)h;
    float2 acc = hp[(size_t)wid * 64 + lane];
    for (int base = beg; base < end; base += 64) {
        int cnt = end - base;
        if (cnt > 64) cnt = 64;
        int idx = (lane < cnt) ? csr_src[base + lane] : 0;
        int j = 0;
        for (; j + 8 <= cnt; j += 8) {
            int s0 = __shfl(idx, j);
            int s1 = __shfl(idx, j + 1);
            int s2 = __shfl(idx, j + 2);
            int s3 = __shfl(idx, j + 3);
            int s4 = __shfl(idx, j + 4);
            int s5 = __shfl(idx, j + 5);
            int s6 = __shfl(idx, j + 6);
            int s7 = __shfl(idx, j + 7);
            float2 v0 = hp[(size_t)s0 * 64 + lane];
            float2 v1 = hp[(size_t)s1 * 64 + lane];
            float2 v2 = hp[(size_t)s2 * 64 + lane];
            float2 v3 = hp[(size_t)s3 * 64 + lane];
            float2 v4 = hp[(size_t)s4 * 64 + lane];
            float2 v5 = hp[(size_t)s5 * 64 + lane];
            float2 v6 = hp[(size_t)s6 * 64 + lane];
            float2 v7 = hp[(size_t)s7 * 64 + lane];
            acc.x += v0.x; acc.y += v0.y;
            acc.x += v1.x; acc.y += v1.y;
            acc.x += v2.x; acc.y += v2.y;
            acc.x += v3.x; acc.y += v3.y;
            acc.x += v4.x; acc.y += v4.y;
            acc.x += v5.x; acc.y += v5.y;
            acc.x += v6.x; acc.y += v6.y;
            acc.x += v7.x; acc.y += v7.y;
        }
        for (; j < cnt; ++j) {
            int s = __shfl(idx, j);
            float2 v = hp[(size_t)s * 64 + lane];
            acc.x += v.x;
            acc.y += v.y;
        }
    }
    u16 h0, l0, h1, l1;
    split_bf16(acc.x, &h0, &l0);
    split_bf16(acc.y, &h1, &l1);
    ushort2 vh; vh.x = h0; vh.y = h1;
    ushort2 vl; vl.x = l0; vl.y = l1;
    ((ushort2*)zhi)[(size_t)wid * 64 + lane] = vh;
    ((ushort2*)zlo)[(size_t)wid * 64 + lane] = vl;
}

// -------- split + transpose GIN weights: w1t[l][n][k], w2t[l][n][k] --------
__global__ __launch_bounds__(256) void prep_weights_kernel(const float* __restrict__ gw1,
                                                           const float* __restrict__ gw2,
                                                           u16* __restrict__ w1hi, u16* __restrict__ w1lo,
                                                           u16* __restrict__ w2hi, u16* __restrict__ w2lo) {
    int i = blockIdx.x * 256 + threadIdx.x;
    if (i >= NL * 32768) return;
    int l = i / 32768, rem = i % 32768;
    int n1 = rem >> 7, k1 = rem & 127;
    split_bf16(gw1[(size_t)l * 32768 + (size_t)k1 * 256 + n1], &w1hi[i], &w1lo[i]);
    int n2 = rem >> 8, k2 = rem & 255;
    split_bf16(gw2[(size_t)l * 32768 + (size_t)k2 * 128 + n2], &w2hi[i], &w2lo[i]);
}

// ======== fused MLP: z2 = (relu(z@W1+b1))@W2 + b2, z1 stays in LDS ========
// 64-row tile, 256 threads (4 waves). LDS: zA hi/lo [64][128] (32 KB, staged once,
// XOR-swizzle chunk^=(row&15)) + z1buf hi/lo [64][128] (32 KB, per 128-col half).
// GEMM1: per half, per wave 64rows x 32cols of z1 -> LDS. GEMM2: acc2 += z1half @ W2t.
// Per-accumulator MFMA order identical to the unfused r7 kernels (bit-exact).
__global__ __launch_bounds__(256) void gin_mlp(const u16* __restrict__ zH, const u16* __restrict__ zL,
                                               const u16* __restrict__ W1h, const u16* __restrict__ W1l,
                                               const u16* __restrict__ W2h, const u16* __restrict__ W2l,
                                               const float* __restrict__ b1, const float* __restrict__ b2,
                                               float* __restrict__ Of, float* __restrict__ sums) {
    __shared__ __align__(16) u16 zh[8192], zl[8192];    // z tile [64][128]
    __shared__ __align__(16) u16 z1h[8192], z1l[8192];  // z1 half [64][128]
    const int t = threadIdx.x;
    const int wv = t >> 6, lane = t & 63;
    const int l15 = lane & 15, l4 = lane >> 4;
    const int m0 = blockIdx.x * 64;

    // ---- stage z tile (hi/lo), inverse-swizzled global source ----
    {
        int rlo = lane >> 4;     // row within 4-row group
        int cpos = lane & 15;    // 16B chunk 0..15
        for (int i = 0; i < 4; ++i) {
            int lrow = wv * 16 + i * 4 + rlo;
            int sc = cpos ^ (lrow & 15);
            gload_lds16(zH + (size_t)(m0 + lrow) * 128 + sc * 8, zh + wv * 2048 + i * 512);
            gload_lds16(zL + (size_t)(m0 + lrow) * 128 + sc * 8, zl + wv * 2048 + i * 512);
        }
    }
    __syncthreads();

    f32x4 a2[4][2];
#pragma unroll
    for (int m = 0; m < 4; ++m)
#pragma unroll
        for (int n = 0; n < 2; ++n)
            a2[m][n] = (f32x4){0.f, 0.f, 0.f, 0.f};

    for (int half = 0; half < 2; ++half) {
        // ---- GEMM1: z1_half[64][128], this wave: cols wv*32..wv*32+31 ----
        f32x4 a1[4][2];
#pragma unroll
        for (int m = 0; m < 4; ++m)
#pragma unroll
            for (int n = 0; n < 2; ++n)
                a1[m][n] = (f32x4){0.f, 0.f, 0.f, 0.f};

#pragma unroll
        for (int ks = 0; ks < 4; ++ks) {
            short8v ah[4], al[4];
#pragma unroll
            for (int m = 0; m < 4; ++m) {
                int rA = m * 16 + l15;
                int au = rA * 128 + (((ks * 4 + l4) ^ (rA & 15)) << 3);
                ah[m] = *(const short8v*)(zh + au);
                al[m] = *(const short8v*)(zl + au);
            }
#pragma unroll
            for (int n = 0; n < 2; ++n) {
                int col = half * 128 + wv * 32 + n * 16 + l15;
                short8v bh = *(const short8v*)(W1h + (size_t)col * 128 + ks * 32 + l4 * 8);
                short8v bl = *(const short8v*)(W1l + (size_t)col * 128 + ks * 32 + l4 * 8);
#pragma unroll
                for (int m = 0; m < 4; ++m) {
                    a1[m][n] = __builtin_amdgcn_mfma_f32_16x16x32_bf16(ah[m], bh, a1[m][n], 0, 0, 0);
                    a1[m][n] = __builtin_amdgcn_mfma_f32_16x16x32_bf16(ah[m], bl, a1[m][n], 0, 0, 0);
                    a1[m][n] = __builtin_amdgcn_mfma_f32_16x16x32_bf16(al[m], bh, a1[m][n], 0, 0, 0);
                }
            }
        }
        __syncthreads();  // prior half's z1buf readers done
        // ---- epilogue -> z1buf (swizzled; conflict-free by row-XOR) ----
#pragma unroll
        for (int n = 0; n < 2; ++n) {
            int colL = wv * 32 + n * 16 + l15;
            float bv = b1[half * 128 + colL];
#pragma unroll
            for (int m = 0; m < 4; ++m) {
#pragma unroll
                for (int r = 0; r < 4; ++r) {
                    int row = m * 16 + l4 * 4 + r;
                    float v = fmaxf(a1[m][n][r] + bv, 0.f);
                    u16 hi, lo;
                    split_bf16(v, &hi, &lo);
                    int addr = row * 128 + (((colL >> 3) ^ (row & 15)) << 3) + (colL & 7);
                    z1h[addr] = hi;
                    z1l[addr] = lo;
                }
            }
        }
        __syncthreads();
        // ---- GEMM2 partial: a2 += z1_half @ W2t[:, half k-slice] ----
#pragma unroll
        for (int ks = 0; ks < 4; ++ks) {
            short8v ah[4], al[4];
#pragma unroll
            for (int m = 0; m < 4; ++m) {
                int rA = m * 16 + l15;
                int au = rA * 128 + (((ks * 4 + l4) ^ (rA & 15)) << 3);
                ah[m] = *(const short8v*)(z1h + au);
                al[m] = *(const short8v*)(z1l + au);
            }
#pragma unroll
            for (int n = 0; n < 2; ++n) {
                int col = wv * 32 + n * 16 + l15;
                int kk = half * 128 + ks * 32 + l4 * 8;
                short8v bh = *(const short8v*)(W2h + (size_t)col * 256 + kk);
                short8v bl = *(const short8v*)(W2l + (size_t)col * 256 + kk);
#pragma unroll
                for (int m = 0; m < 4; ++m) {
                    a2[m][n] = __builtin_amdgcn_mfma_f32_16x16x32_bf16(ah[m], bh, a2[m][n], 0, 0, 0);
                    a2[m][n] = __builtin_amdgcn_mfma_f32_16x16x32_bf16(ah[m], bl, a2[m][n], 0, 0, 0);
                    a2[m][n] = __builtin_amdgcn_mfma_f32_16x16x32_bf16(al[m], bh, a2[m][n], 0, 0, 0);
                }
            }
        }
    }

    // ---- epilogue: bias, store z2 fp32, BN stats ----
#pragma unroll
    for (int n = 0; n < 2; ++n) {
        int gcol = wv * 32 + n * 16 + l15;
        float bv = b2[gcol];
        float s = 0.f, q = 0.f;
#pragma unroll
        for (int m = 0; m < 4; ++m) {
#pragma unroll
            for (int r = 0; r < 4; ++r) {
                int grow = m0 + m * 16 + l4 * 4 + r;
                float v = a2[m][n][r] + bv;
                Of[(size_t)grow * HD + gcol] = v;
                if (grow < NN) { s += v; q += v * v; }
            }
        }
        s += __shfl_xor(s, 16); s += __shfl_xor(s, 32);
        q += __shfl_xor(q, 16); q += __shfl_xor(q, 32);
        if (l4 == 0) {
            atomicAdd(&sums[gcol], s);
            atomicAdd(&sums[128 + gcol], q);
        }
    }
}

__global__ void bn_finalize_kernel(const float* __restrict__ sums,
                                   const float* __restrict__ gamma,
                                   const float* __restrict__ beta,
                                   float* __restrict__ scale, float* __restrict__ shift) {
    int c = threadIdx.x;  // 128
    float mean = sums[c] / (float)NN;
    float var = sums[128 + c] / (float)NN - mean * mean;
    float rstd = rsqrtf(fmaxf(var, 0.f) + BN_EPS);
    float sc = rstd * gamma[c];
    scale[c] = sc;
    shift[c] = beta[c] - mean * sc;
}

// -------- h = relu(z2*scale+shift) (+ h residual), in-place on h --------
__global__ __launch_bounds__(256) void bn_apply_kernel(const float* __restrict__ z2,
                                                       const float* __restrict__ scale,
                                                       const float* __restrict__ shift,
                                                       float* __restrict__ h, int use_res) {
    int i = blockIdx.x * 256 + threadIdx.x;
    if (i >= NN * 32) return;
    int c4 = (i & 31) * 4;
    float4 v = ((const float4*)z2)[i];
    float4 sc = *(const float4*)(scale + c4);
    float4 sh = *(const float4*)(shift + c4);
    float4 o;
    o.x = fmaxf(v.x * sc.x + sh.x, 0.f);
    o.y = fmaxf(v.y * sc.y + sh.y, 0.f);
    o.z = fmaxf(v.z * sc.z + sh.z, 0.f);
    o.w = fmaxf(v.w * sc.w + sh.w, 0.f);
    if (use_res) {
        float4 r = ((float4*)h)[i];
        o.x += r.x; o.y += r.y; o.z += r.z; o.w += r.w;
    }
    ((float4*)h)[i] = o;
}

// ---------------- pooling: chunked partials + combine (batch sorted) ----------------
__global__ __launch_bounds__(256) void pool_part_kernel(const float* __restrict__ h,
                                                        const int* __restrict__ batch,
                                                        float* __restrict__ psum,
                                                        float* __restrict__ pmax) {
    __shared__ int bounds[2];
    __shared__ float redS[256], redM[256];
    int g = blockIdx.x, chunk = blockIdx.y, t = threadIdx.x;
    if (t < 2) {
        int target = g + t, lo = 0, hi = NN;
        while (lo < hi) {
            int mid = (lo + hi) >> 1;
            if (batch[mid] < target) lo = mid + 1;
            else hi = mid;
        }
        bounds[t] = lo;
    }
    __syncthreads();
    int lo = bounds[0], hi = bounds[1], len = hi - lo;
    int c0 = lo + (len * chunk) / PCH;
    int c1 = lo + (len * (chunk + 1)) / PCH;
    int c = t & 127, half = t >> 7;
    float s = 0.f, m = -3.4e38f;
    for (int r = c0 + half; r < c1; r += 2) {
        float v = h[(size_t)r * HD + c];
        s += v;
        m = fmaxf(m, v);
    }
    redS[t] = s;
    redM[t] = m;
    __syncthreads();
    if (t < 128) {
        psum[((size_t)g * PCH + chunk) * HD + t] = redS[t] + redS[t + 128];
        pmax[((size_t)g * PCH + chunk) * HD + t] = fmaxf(redM[t], redM[t + 128]);
    }
}

__global__ __launch_bounds__(128) void pool_combine_kernel(const float* __restrict__ psum,
                                                           const float* __restrict__ pmax,
                                                           const int* __restrict__ batch,
                                                           float* __restrict__ emb) {
    __shared__ int bounds[2];
    int g = blockIdx.x, t = threadIdx.x;
    if (t < 2) {
        int target = g + t, lo = 0, hi = NN;
        while (lo < hi) {
            int mid = (lo + hi) >> 1;
            if (batch[mid] < target) lo = mid + 1;
            else hi = mid;
        }
        bounds[t] = lo;
    }
    __syncthreads();
    int len = bounds[1] - bounds[0];
    float s = 0.f, m = -3.4e38f;
#pragma unroll
    for (int ch = 0; ch < PCH; ++ch) {
        s += psum[((size_t)g * PCH + ch) * HD + t];
        m = fmaxf(m, pmax[((size_t)g * PCH + ch) * HD + t]);
    }
    float mean;
    if (len > 0) {
        mean = s / (float)len;
    } else {
        mean = 0.f; m = 0.f; s = 0.f;
    }
    emb[g * 384 + t] = mean;
    emb[g * 384 + 128 + t] = m;
    emb[g * 384 + 256 + t] = s;
}

// ---------------- head MLP: one block per graph ----------------
__global__ __launch_bounds__(256) void head_kernel(const float* __restrict__ emb,
                                                   const float* __restrict__ w1, const float* __restrict__ b1,
                                                   const float* __restrict__ w2, const float* __restrict__ b2,
                                                   const float* __restrict__ cw, const float* __restrict__ cb,
                                                   float* __restrict__ out) {
    __shared__ float e[384], f1[256], f2[128];
    int g = blockIdx.x, t = threadIdx.x;
    e[t] = emb[g * 384 + t];
    if (t < 128) e[256 + t] = emb[g * 384 + 256 + t];
    __syncthreads();
    float acc = b1[t];
    for (int k = 0; k < 384; ++k) acc += e[k] * w1[(size_t)k * 256 + t];
    f1[t] = fmaxf(acc, 0.f);
    __syncthreads();
    if (t < 128) {
        float a2 = b2[t];
        for (int k = 0; k < 256; ++k) a2 += f1[k] * w2[k * 128 + t];
        f2[t] = fmaxf(a2, 0.f);
    }
    __syncthreads();
    if (t < 4) {
        float a3 = cb[t];
        for (int k = 0; k < 128; ++k) a3 += f2[k] * cw[k * 4 + t];
        out[g * 4 + t] = a3;
    }
}

// ---------------- launch ----------------
extern "C" void kernel_launch(void* const* d_in, const int* in_sizes, int n_in,
                              void* d_out, int out_size, void* d_ws, size_t ws_size,
                              hipStream_t stream) {
    const int* x = (const int*)d_in[0];
    const int* edge = (const int*)d_in[1];
    const int* batch = (const int*)d_in[2];
    const float* node_emb = (const float*)d_in[3];
    const float* comp_emb = (const float*)d_in[4];
    const float* pin_emb = (const float*)d_in[5];
    const float* proj_w = (const float*)d_in[6];
    const float* proj_b = (const float*)d_in[7];
    const float* gin_w1 = (const float*)d_in[8];
    const float* gin_b1 = (const float*)d_in[9];
    const float* gin_w2 = (const float*)d_in[10];
    const float* gin_b2 = (const float*)d_in[11];
    const float* bn_gamma = (const float*)d_in[12];
    const float* bn_beta = (const float*)d_in[13];
    const float* fus_w1 = (const float*)d_in[14];
    const float* fus_b1 = (const float*)d_in[15];
    const float* fus_w2 = (const float*)d_in[16];
    const float* fus_b2 = (const float*)d_in[17];
    const float* cls_w = (const float*)d_in[18];
    const float* cls_b = (const float*)d_in[19];

    const int* esrc = edge;
    const int* edst = edge + NE;

    char* ws = (char*)d_ws;
    size_t off = 0;
    auto alloc = [&](size_t bytes) -> void* {
        void* p = ws + off;
        off = (off + bytes + 255) & ~(size_t)255;
        return p;
    };
    float* h = (float*)alloc((size_t)NN * HD * 4);      // node features (fp32)
    u16* z_hi = (u16*)alloc((size_t)MPAD * HD * 2);     // segsum out hi
    u16* z_lo = (u16*)alloc((size_t)MPAD * HD * 2);     // segsum out lo
    float* z2 = (float*)alloc((size_t)MPAD * HD * 4);   // gin_mlp out (fp32)
    u16* w1hi = (u16*)alloc((size_t)NL * 32768 * 2);
    u16* w1lo = (u16*)alloc((size_t)NL * 32768 * 2);
    u16* w2hi = (u16*)alloc((size_t)NL * 32768 * 2);
    u16* w2lo = (u16*)alloc((size_t)NL * 32768 * 2);
    float* P = (float*)alloc(17 * HD * 4);
    float* sums = (float*)alloc(256 * 4);
    float* scale = (float*)alloc(HD * 4);
    float* shift = (float*)alloc(HD * 4);
    float* emb = (float*)alloc((size_t)NG * 384 * 4);
    float* psum = (float*)alloc((size_t)NG * PCH * HD * 4);
    float* pmax = (float*)alloc((size_t)NG * PCH * HD * 4);
    int* deg = (int*)alloc((size_t)NN * 4);
    int* rowstart = (int*)alloc((size_t)(NN + 1) * 4);
    int* rank = (int*)alloc((size_t)NE * 4);
    int* csr_src = (int*)alloc((size_t)NE * 4);
    int* partials = (int*)alloc(64 * 4);

    // embedding + projection + weight prep
    proj_tables_kernel<<<1, 128, 0, stream>>>(node_emb, comp_emb, pin_emb, proj_w, P);
    embed_kernel<<<(NN * 32 + 255) / 256, 256, 0, stream>>>(x, P, proj_b, h);
    prep_weights_kernel<<<(NL * 32768 + 255) / 256, 256, 0, stream>>>(gin_w1, gin_w2,
                                                                      w1hi, w1lo, w2hi, w2lo);

    // CSR build (once per call; atomics only in hist, ranks recorded)
    hipMemsetAsync(deg, 0, (size_t)NN * 4, stream);
    hist_kernel<<<(NE + 255) / 256, 256, 0, stream>>>(edst, deg, rank);
    int nblk = (NN + 2047) / 2048;  // 49
    scan1_kernel<<<nblk, 256, 0, stream>>>(deg, rowstart, partials);
    scan2_kernel<<<1, 64, 0, stream>>>(partials, rowstart, nblk);
    scan3_kernel<<<(NN + 255) / 256, 256, 0, stream>>>(rowstart, partials);
    fill_kernel<<<(NE + 255) / 256, 256, 0, stream>>>(esrc, edst, rowstart, rank, csr_src);

    const int gm = MPAD / 64;  // 1564
    for (int l = 0; l < NL; ++l) {
        segsum_kernel<<<(NN * 64 + 255) / 256, 256, 0, stream>>>(h, rowstart, csr_src, z_hi, z_lo);
        hipMemsetAsync(sums, 0, 256 * 4, stream);
        gin_mlp<<<gm, 256, 0, stream>>>(z_hi, z_lo,
                                        w1hi + (size_t)l * 32768, w1lo + (size_t)l * 32768,
                                        w2hi + (size_t)l * 32768, w2lo + (size_t)l * 32768,
                                        gin_b1 + (size_t)l * 256, gin_b2 + (size_t)l * HD,
                                        z2, sums);
        bn_finalize_kernel<<<1, 128, 0, stream>>>(sums, bn_gamma + l * HD, bn_beta + l * HD, scale, shift);
        bn_apply_kernel<<<(NN * 32 + 255) / 256, 256, 0, stream>>>(z2, scale, shift, h, l > 0 ? 1 : 0);
    }

    pool_part_kernel<<<dim3(NG, PCH), 256, 0, stream>>>(h, batch, psum, pmax);
    pool_combine_kernel<<<NG, 128, 0, stream>>>(psum, pmax, batch, emb);
    head_kernel<<<NG, 256, 0, stream>>>(emb, fus_w1, fus_b1, fus_w2, fus_b2, cls_w, cls_b,
                                        (float*)d_out);
}

// Round 11
// 896.320 us; speedup vs baseline: 1.3765x; 1.1581x over previous
//
#include <hip/hip_runtime.h>
#include <hip/hip_bf16.h>

// FEGIN: GIN graph encoder + classifier.
// segsum: CSR gather from a bf16 shadow of h (halves gather bytes); self-term fp32.
// gin_mlp: fused GEMM1+GEMM2 per 64-row tile, z1 in LDS, split-bf16 3-pass MFMA,
// BN-stats fused epilogue. CSR rank-trick build. Chunked pool. Fused head MLP.

#define NN 100000
#define NE 1600000
#define HD 128
#define NG 128
#define NL 3
#define BN_EPS 1e-5f
#define MPAD 100096   // 1564 * 64
#define PCH 8         // pool chunks per graph

typedef unsigned short u16;
typedef unsigned int u32;
typedef __attribute__((ext_vector_type(8))) short short8v;
typedef __attribute__((ext_vector_type(4))) float f32x4;

__device__ inline u16 bf16_hi(float v) {
    __hip_bfloat16 h = __float2bfloat16(v);
    return *(u16*)&h;
}
__device__ inline float bf16_f(u16 u) {
    __hip_bfloat16 h = *(__hip_bfloat16*)&u;
    return __bfloat162float(h);
}
__device__ inline void split_bf16(float v, u16* hi, u16* lo) {
    u16 h = bf16_hi(v);
    *hi = h;
    *lo = bf16_hi(v - bf16_f(h));
}

// async 16B global->LDS (wave-uniform LDS base; HW adds lane*16)
__device__ inline void gload_lds16(const void* g, void* l) {
    __builtin_amdgcn_global_load_lds(
        (const __attribute__((address_space(1))) void*)g,
        (__attribute__((address_space(3))) void*)l, 16, 0, 0);
}

// ---------------- projected embedding tables: P[17][128] ----------------
__global__ void proj_tables_kernel(const float* __restrict__ node_emb,
                                   const float* __restrict__ comp_emb,
                                   const float* __restrict__ pin_emb,
                                   const float* __restrict__ proj_w,
                                   float* __restrict__ P) {
    int c = threadIdx.x;  // 0..127
    for (int r = 0; r < 17; ++r) {
        const float* emb;
        int base;
        if (r < 5)        { emb = node_emb + r * HD;        base = 0; }
        else if (r < 11)  { emb = comp_emb + (r - 5) * HD;  base = HD; }
        else              { emb = pin_emb + (r - 11) * HD;  base = 2 * HD; }
        float acc = 0.f;
        for (int k = 0; k < HD; ++k)
            acc += emb[k] * proj_w[(size_t)(base + k) * HD + c];
        P[r * HD + c] = acc;
    }
}

// ------- h0 = P0[x0]+P1[x1]+P2[x2]+proj_b; also emit bf16 shadow hb -------
__global__ __launch_bounds__(256) void embed_kernel(const int* __restrict__ x,
                                                    const float* __restrict__ P,
                                                    const float* __restrict__ proj_b,
                                                    float* __restrict__ h,
                                                    u16* __restrict__ hb) {
    int i = blockIdx.x * 256 + threadIdx.x;
    int n = i >> 5;
    if (n >= NN) return;
    int c4 = (i & 31) * 4;
    int i0 = x[3 * n + 0]; i0 = i0 < 0 ? 0 : (i0 > 4 ? 4 : i0);
    int i1 = x[3 * n + 1]; i1 = i1 < 0 ? 0 : (i1 > 5 ? 5 : i1);
    int i2 = x[3 * n + 2]; i2 = i2 < 0 ? 0 : (i2 > 5 ? 5 : i2);
    float4 a = *(const float4*)(P + i0 * HD + c4);
    float4 b = *(const float4*)(P + (5 + i1) * HD + c4);
    float4 c = *(const float4*)(P + (11 + i2) * HD + c4);
    float4 bb = *(const float4*)(proj_b + c4);
    float4 o;
    o.x = a.x + b.x + c.x + bb.x;
    o.y = a.y + b.y + c.y + bb.y;
    o.z = a.z + b.z + c.z + bb.z;
    o.w = a.w + b.w + c.w + bb.w;
    *(float4*)(h + (size_t)n * HD + c4) = o;
    ushort4 s;
    s.x = bf16_hi(o.x); s.y = bf16_hi(o.y); s.z = bf16_hi(o.z); s.w = bf16_hi(o.w);
    *(ushort4*)(hb + (size_t)n * HD + c4) = s;
}

// ---------------- CSR build (rank trick: atomics only in hist) ----------------
__global__ void hist_kernel(const int* __restrict__ dst, int* __restrict__ deg,
                            int* __restrict__ rank) {
    int e = blockIdx.x * 256 + threadIdx.x;
    if (e < NE) rank[e] = atomicAdd(&deg[dst[e]], 1);
}

__global__ __launch_bounds__(256) void scan1_kernel(const int* __restrict__ deg,
                                                    int* __restrict__ rowstart,
                                                    int* __restrict__ partials) {
    __shared__ int arr[256];
    int blk = blockIdx.x, t = threadIdx.x;
    int base = blk * 2048 + t * 8;
    int v[8];
    int s = 0;
#pragma unroll
    for (int j = 0; j < 8; ++j) {
        int idx = base + j;
        int d = (idx < NN) ? deg[idx] : 0;
        v[j] = s;
        s += d;
    }
    int own = s;
    arr[t] = s;
    __syncthreads();
    for (int off = 1; off < 256; off <<= 1) {
        int add = (t >= off) ? arr[t - off] : 0;
        __syncthreads();
        arr[t] += add;
        __syncthreads();
    }
    int excl = arr[t] - own;
#pragma unroll
    for (int j = 0; j < 8; ++j) {
        int idx = base + j;
        if (idx < NN) rowstart[idx] = excl + v[j];
    }
    if (t == 255) partials[blk] = arr[255];
}

__global__ void scan2_kernel(int* __restrict__ partials, int* __restrict__ rowstart, int nblk) {
    if (threadIdx.x == 0) {
        int run = 0;
        for (int b = 0; b < nblk; ++b) {
            int p = partials[b];
            partials[b] = run;
            run += p;
        }
        rowstart[NN] = run;
    }
}

__global__ void scan3_kernel(int* __restrict__ rowstart, const int* __restrict__ partials) {
    int i = blockIdx.x * 256 + threadIdx.x;
    if (i < NN) rowstart[i] += partials[i >> 11];
}

__global__ void fill_kernel(const int* __restrict__ src, const int* __restrict__ dst,
                            const int* __restrict__ rowstart, const int* __restrict__ rank,
                            int* __restrict__ csr_src) {
    int e = blockIdx.x * 256 + threadIdx.x;
    if (e < NE) csr_src[rowstart[dst[e]] + rank[e]] = src[e];
}

// -------- z = h + sum_{in-edges} hb[src] (bf16 gather); emit hi/lo planes --------
// one wave per node; 64 edge indices loaded coalesced, rows gathered 8-deep.
__global__ __launch_bounds__(256) void segsum_kernel(const float* __restrict__ h,
                                                     const u16* __restrict__ hb,
                                                     const int* __restrict__ rowstart,
                                                     const int* __restrict__ csr_src,
                                                     u16* __restrict__ zhi,
                                                     u16* __restrict__ zlo) {
    int wid = (blockIdx.x * 256 + threadIdx.x) >> 6;
    int lane = threadIdx.x & 63;
    if (wid >= NN) return;
    int beg = __builtin_amdgcn_readfirstlane(rowstart[wid]);
    int end = __builtin_amdgcn_readfirstlane(rowstart[wid + 1]);
    const float2* hp = (const float2*)h;
    float2 acc = hp[(size_t)wid * 64 + lane];   // self-term fp32
    const ushort2* hbp = (const ushort2*)hb;
    for (int base = beg; base < end; base += 64) {
        int cnt = end - base;
        if (cnt > 64) cnt = 64;
        int idx = (lane < cnt) ? csr_src[base + lane] : 0;
        int j = 0;
        for (; j + 8 <= cnt; j += 8) {
            int s0 = __shfl(idx, j);
            int s1 = __shfl(idx, j + 1);
            int s2 = __shfl(idx, j + 2);
            int s3 = __shfl(idx, j + 3);
            int s4 = __shfl(idx, j + 4);
            int s5 = __shfl(idx, j + 5);
            int s6 = __shfl(idx, j + 6);
            int s7 = __shfl(idx, j + 7);
            ushort2 v0 = hbp[(size_t)s0 * 64 + lane];
            ushort2 v1 = hbp[(size_t)s1 * 64 + lane];
            ushort2 v2 = hbp[(size_t)s2 * 64 + lane];
            ushort2 v3 = hbp[(size_t)s3 * 64 + lane];
            ushort2 v4 = hbp[(size_t)s4 * 64 + lane];
            ushort2 v5 = hbp[(size_t)s5 * 64 + lane];
            ushort2 v6 = hbp[(size_t)s6 * 64 + lane];
            ushort2 v7 = hbp[(size_t)s7 * 64 + lane];
            acc.x += bf16_f(v0.x); acc.y += bf16_f(v0.y);
            acc.x += bf16_f(v1.x); acc.y += bf16_f(v1.y);
            acc.x += bf16_f(v2.x); acc.y += bf16_f(v2.y);
            acc.x += bf16_f(v3.x); acc.y += bf16_f(v3.y);
            acc.x += bf16_f(v4.x); acc.y += bf16_f(v4.y);
            acc.x += bf16_f(v5.x); acc.y += bf16_f(v5.y);
            acc.x += bf16_f(v6.x); acc.y += bf16_f(v6.y);
            acc.x += bf16_f(v7.x); acc.y += bf16_f(v7.y);
        }
        for (; j < cnt; ++j) {
            int s = __shfl(idx, j);
            ushort2 v = hbp[(size_t)s * 64 + lane];
            acc.x += bf16_f(v.x);
            acc.y += bf16_f(v.y);
        }
    }
    u16 h0, l0, h1, l1;
    split_bf16(acc.x, &h0, &l0);
    split_bf16(acc.y, &h1, &l1);
    ushort2 vh; vh.x = h0; vh.y = h1;
    ushort2 vl; vl.x = l0; vl.y = l1;
    ((ushort2*)zhi)[(size_t)wid * 64 + lane] = vh;
    ((ushort2*)zlo)[(size_t)wid * 64 + lane] = vl;
}

// -------- split + transpose GIN weights: w1t[l][n][k], w2t[l][n][k] --------
__global__ __launch_bounds__(256) void prep_weights_kernel(const float* __restrict__ gw1,
                                                           const float* __restrict__ gw2,
                                                           u16* __restrict__ w1hi, u16* __restrict__ w1lo,
                                                           u16* __restrict__ w2hi, u16* __restrict__ w2lo) {
    int i = blockIdx.x * 256 + threadIdx.x;
    if (i >= NL * 32768) return;
    int l = i / 32768, rem = i % 32768;
    int n1 = rem >> 7, k1 = rem & 127;
    split_bf16(gw1[(size_t)l * 32768 + (size_t)k1 * 256 + n1], &w1hi[i], &w1lo[i]);
    int n2 = rem >> 8, k2 = rem & 255;
    split_bf16(gw2[(size_t)l * 32768 + (size_t)k2 * 128 + n2], &w2hi[i], &w2lo[i]);
}

// ======== fused MLP: z2 = (relu(z@W1+b1))@W2 + b2, z1 stays in LDS ========
__global__ __launch_bounds__(256) void gin_mlp(const u16* __restrict__ zH, const u16* __restrict__ zL,
                                               const u16* __restrict__ W1h, const u16* __restrict__ W1l,
                                               const u16* __restrict__ W2h, const u16* __restrict__ W2l,
                                               const float* __restrict__ b1, const float* __restrict__ b2,
                                               float* __restrict__ Of, float* __restrict__ sums) {
    __shared__ __align__(16) u16 zh[8192], zl[8192];    // z tile [64][128]
    __shared__ __align__(16) u16 z1h[8192], z1l[8192];  // z1 half [64][128]
    const int t = threadIdx.x;
    const int wv = t >> 6, lane = t & 63;
    const int l15 = lane & 15, l4 = lane >> 4;
    const int m0 = blockIdx.x * 64;

    // ---- stage z tile (hi/lo), inverse-swizzled global source ----
    {
        int rlo = lane >> 4;
        int cpos = lane & 15;
        for (int i = 0; i < 4; ++i) {
            int lrow = wv * 16 + i * 4 + rlo;
            int sc = cpos ^ (lrow & 15);
            gload_lds16(zH + (size_t)(m0 + lrow) * 128 + sc * 8, zh + wv * 2048 + i * 512);
            gload_lds16(zL + (size_t)(m0 + lrow) * 128 + sc * 8, zl + wv * 2048 + i * 512);
        }
    }
    __syncthreads();

    f32x4 a2[4][2];
#pragma unroll
    for (int m = 0; m < 4; ++m)
#pragma unroll
        for (int n = 0; n < 2; ++n)
            a2[m][n] = (f32x4){0.f, 0.f, 0.f, 0.f};

    for (int half = 0; half < 2; ++half) {
        f32x4 a1[4][2];
#pragma unroll
        for (int m = 0; m < 4; ++m)
#pragma unroll
            for (int n = 0; n < 2; ++n)
                a1[m][n] = (f32x4){0.f, 0.f, 0.f, 0.f};

#pragma unroll
        for (int ks = 0; ks < 4; ++ks) {
            short8v ah[4], al[4];
#pragma unroll
            for (int m = 0; m < 4; ++m) {
                int rA = m * 16 + l15;
                int au = rA * 128 + (((ks * 4 + l4) ^ (rA & 15)) << 3);
                ah[m] = *(const short8v*)(zh + au);
                al[m] = *(const short8v*)(zl + au);
            }
#pragma unroll
            for (int n = 0; n < 2; ++n) {
                int col = half * 128 + wv * 32 + n * 16 + l15;
                short8v bh = *(const short8v*)(W1h + (size_t)col * 128 + ks * 32 + l4 * 8);
                short8v bl = *(const short8v*)(W1l + (size_t)col * 128 + ks * 32 + l4 * 8);
#pragma unroll
                for (int m = 0; m < 4; ++m) {
                    a1[m][n] = __builtin_amdgcn_mfma_f32_16x16x32_bf16(ah[m], bh, a1[m][n], 0, 0, 0);
                    a1[m][n] = __builtin_amdgcn_mfma_f32_16x16x32_bf16(ah[m], bl, a1[m][n], 0, 0, 0);
                    a1[m][n] = __builtin_amdgcn_mfma_f32_16x16x32_bf16(al[m], bh, a1[m][n], 0, 0, 0);
                }
            }
        }
        __syncthreads();
#pragma unroll
        for (int n = 0; n < 2; ++n) {
            int colL = wv * 32 + n * 16 + l15;
            float bv = b1[half * 128 + colL];
#pragma unroll
            for (int m = 0; m < 4; ++m) {
#pragma unroll
                for (int r = 0; r < 4; ++r) {
                    int row = m * 16 + l4 * 4 + r;
                    float v = fmaxf(a1[m][n][r] + bv, 0.f);
                    u16 hi, lo;
                    split_bf16(v, &hi, &lo);
                    int addr = row * 128 + (((colL >> 3) ^ (row & 15)) << 3) + (colL & 7);
                    z1h[addr] = hi;
                    z1l[addr] = lo;
                }
            }
        }
        __syncthreads();
#pragma unroll
        for (int ks = 0; ks < 4; ++ks) {
            short8v ah[4], al[4];
#pragma unroll
            for (int m = 0; m < 4; ++m) {
                int rA = m * 16 + l15;
                int au = rA * 128 + (((ks * 4 + l4) ^ (rA & 15)) << 3);
                ah[m] = *(const short8v*)(z1h + au);
                al[m] = *(const short8v*)(z1l + au);
            }
#pragma unroll
            for (int n = 0; n < 2; ++n) {
                int col = wv * 32 + n * 16 + l15;
                int kk = half * 128 + ks * 32 + l4 * 8;
                short8v bh = *(const short8v*)(W2h + (size_t)col * 256 + kk);
                short8v bl = *(const short8v*)(W2l + (size_t)col * 256 + kk);
#pragma unroll
                for (int m = 0; m < 4; ++m) {
                    a2[m][n] = __builtin_amdgcn_mfma_f32_16x16x32_bf16(ah[m], bh, a2[m][n], 0, 0, 0);
                    a2[m][n] = __builtin_amdgcn_mfma_f32_16x16x32_bf16(ah[m], bl, a2[m][n], 0, 0, 0);
                    a2[m][n] = __builtin_amdgcn_mfma_f32_16x16x32_bf16(al[m], bh, a2[m][n], 0, 0, 0);
                }
            }
        }
    }

    // ---- epilogue: bias, store z2 fp32, BN stats ----
#pragma unroll
    for (int n = 0; n < 2; ++n) {
        int gcol = wv * 32 + n * 16 + l15;
        float bv = b2[gcol];
        float s = 0.f, q = 0.f;
#pragma unroll
        for (int m = 0; m < 4; ++m) {
#pragma unroll
            for (int r = 0; r < 4; ++r) {
                int grow = m0 + m * 16 + l4 * 4 + r;
                float v = a2[m][n][r] + bv;
                Of[(size_t)grow * HD + gcol] = v;
                if (grow < NN) { s += v; q += v * v; }
            }
        }
        s += __shfl_xor(s, 16); s += __shfl_xor(s, 32);
        q += __shfl_xor(q, 16); q += __shfl_xor(q, 32);
        if (l4 == 0) {
            atomicAdd(&sums[gcol], s);
            atomicAdd(&sums[128 + gcol], q);
        }
    }
}

__global__ void bn_finalize_kernel(const float* __restrict__ sums,
                                   const float* __restrict__ gamma,
                                   const float* __restrict__ beta,
                                   float* __restrict__ scale, float* __restrict__ shift) {
    int c = threadIdx.x;  // 128
    float mean = sums[c] / (float)NN;
    float var = sums[128 + c] / (float)NN - mean * mean;
    float rstd = rsqrtf(fmaxf(var, 0.f) + BN_EPS);
    float sc = rstd * gamma[c];
    scale[c] = sc;
    shift[c] = beta[c] - mean * sc;
}

// -------- h = relu(z2*scale+shift) (+ h residual), in-place; emit bf16 shadow --------
__global__ __launch_bounds__(256) void bn_apply_kernel(const float* __restrict__ z2,
                                                       const float* __restrict__ scale,
                                                       const float* __restrict__ shift,
                                                       float* __restrict__ h,
                                                       u16* __restrict__ hb, int use_res) {
    int i = blockIdx.x * 256 + threadIdx.x;
    if (i >= NN * 32) return;
    int c4 = (i & 31) * 4;
    float4 v = ((const float4*)z2)[i];
    float4 sc = *(const float4*)(scale + c4);
    float4 sh = *(const float4*)(shift + c4);
    float4 o;
    o.x = fmaxf(v.x * sc.x + sh.x, 0.f);
    o.y = fmaxf(v.y * sc.y + sh.y, 0.f);
    o.z = fmaxf(v.z * sc.z + sh.z, 0.f);
    o.w = fmaxf(v.w * sc.w + sh.w, 0.f);
    if (use_res) {
        float4 r = ((float4*)h)[i];
        o.x += r.x; o.y += r.y; o.z += r.z; o.w += r.w;
    }
    ((float4*)h)[i] = o;
    ushort4 s;
    s.x = bf16_hi(o.x); s.y = bf16_hi(o.y); s.z = bf16_hi(o.z); s.w = bf16_hi(o.w);
    ((ushort4*)hb)[i] = s;
}

// ---------------- pooling: chunked partials + combine (batch sorted) ----------------
__global__ __launch_bounds__(256) void pool_part_kernel(const float* __restrict__ h,
                                                        const int* __restrict__ batch,
                                                        float* __restrict__ psum,
                                                        float* __restrict__ pmax) {
    __shared__ int bounds[2];
    __shared__ float redS[256], redM[256];
    int g = blockIdx.x, chunk = blockIdx.y, t = threadIdx.x;
    if (t < 2) {
        int target = g + t, lo = 0, hi = NN;
        while (lo < hi) {
            int mid = (lo + hi) >> 1;
            if (batch[mid] < target) lo = mid + 1;
            else hi = mid;
        }
        bounds[t] = lo;
    }
    __syncthreads();
    int lo = bounds[0], hi = bounds[1], len = hi - lo;
    int c0 = lo + (len * chunk) / PCH;
    int c1 = lo + (len * (chunk + 1)) / PCH;
    int c = t & 127, half = t >> 7;
    float s = 0.f, m = -3.4e38f;
    for (int r = c0 + half; r < c1; r += 2) {
        float v = h[(size_t)r * HD + c];
        s += v;
        m = fmaxf(m, v);
    }
    redS[t] = s;
    redM[t] = m;
    __syncthreads();
    if (t < 128) {
        psum[((size_t)g * PCH + chunk) * HD + t] = redS[t] + redS[t + 128];
        pmax[((size_t)g * PCH + chunk) * HD + t] = fmaxf(redM[t], redM[t + 128]);
    }
}

__global__ __launch_bounds__(128) void pool_combine_kernel(const float* __restrict__ psum,
                                                           const float* __restrict__ pmax,
                                                           const int* __restrict__ batch,
                                                           float* __restrict__ emb) {
    __shared__ int bounds[2];
    int g = blockIdx.x, t = threadIdx.x;
    if (t < 2) {
        int target = g + t, lo = 0, hi = NN;
        while (lo < hi) {
            int mid = (lo + hi) >> 1;
            if (batch[mid] < target) lo = mid + 1;
            else hi = mid;
        }
        bounds[t] = lo;
    }
    __syncthreads();
    int len = bounds[1] - bounds[0];
    float s = 0.f, m = -3.4e38f;
#pragma unroll
    for (int ch = 0; ch < PCH; ++ch) {
        s += psum[((size_t)g * PCH + ch) * HD + t];
        m = fmaxf(m, pmax[((size_t)g * PCH + ch) * HD + t]);
    }
    float mean;
    if (len > 0) {
        mean = s / (float)len;
    } else {
        mean = 0.f; m = 0.f; s = 0.f;
    }
    emb[g * 384 + t] = mean;
    emb[g * 384 + 128 + t] = m;
    emb[g * 384 + 256 + t] = s;
}

// ---------------- head MLP: one block per graph ----------------
__global__ __launch_bounds__(256) void head_kernel(const float* __restrict__ emb,
                                                   const float* __restrict__ w1, const float* __restrict__ b1,
                                                   const float* __restrict__ w2, const float* __restrict__ b2,
                                                   const float* __restrict__ cw, const float* __restrict__ cb,
                                                   float* __restrict__ out) {
    __shared__ float e[384], f1[256], f2[128];
    int g = blockIdx.x, t = threadIdx.x;
    e[t] = emb[g * 384 + t];
    if (t < 128) e[256 + t] = emb[g * 384 + 256 + t];
    __syncthreads();
    float acc = b1[t];
    for (int k = 0; k < 384; ++k) acc += e[k] * w1[(size_t)k * 256 + t];
    f1[t] = fmaxf(acc, 0.f);
    __syncthreads();
    if (t < 128) {
        float a2 = b2[t];
        for (int k = 0; k < 256; ++k) a2 += f1[k] * w2[k * 128 + t];
        f2[t] = fmaxf(a2, 0.f);
    }
    __syncthreads();
    if (t < 4) {
        float a3 = cb[t];
        for (int k = 0; k < 128; ++k) a3 += f2[k] * cw[k * 4 + t];
        out[g * 4 + t] = a3;
    }
}

// ---------------- launch ----------------
extern "C" void kernel_launch(void* const* d_in, const int* in_sizes, int n_in,
                              void* d_out, int out_size, void* d_ws, size_t ws_size,
                              hipStream_t stream) {
    const int* x = (const int*)d_in[0];
    const int* edge = (const int*)d_in[1];
    const int* batch = (const int*)d_in[2];
    const float* node_emb = (const float*)d_in[3];
    const float* comp_emb = (const float*)d_in[4];
    const float* pin_emb = (const float*)d_in[5];
    const float* proj_w = (const float*)d_in[6];
    const float* proj_b = (const float*)d_in[7];
    const float* gin_w1 = (const float*)d_in[8];
    const float* gin_b1 = (const float*)d_in[9];
    const float* gin_w2 = (const float*)d_in[10];
    const float* gin_b2 = (const float*)d_in[11];
    const float* bn_gamma = (const float*)d_in[12];
    const float* bn_beta = (const float*)d_in[13];
    const float* fus_w1 = (const float*)d_in[14];
    const float* fus_b1 = (const float*)d_in[15];
    const float* fus_w2 = (const float*)d_in[16];
    const float* fus_b2 = (const float*)d_in[17];
    const float* cls_w = (const float*)d_in[18];
    const float* cls_b = (const float*)d_in[19];

    const int* esrc = edge;
    const int* edst = edge + NE;

    char* ws = (char*)d_ws;
    size_t off = 0;
    auto alloc = [&](size_t bytes) -> void* {
        void* p = ws + off;
        off = (off + bytes + 255) & ~(size_t)255;
        return p;
    };
    float* h = (float*)alloc((size_t)NN * HD * 4);      // node features (fp32)
    u16* hb = (u16*)alloc((size_t)NN * HD * 2);         // bf16 shadow of h
    u16* z_hi = (u16*)alloc((size_t)MPAD * HD * 2);     // segsum out hi
    u16* z_lo = (u16*)alloc((size_t)MPAD * HD * 2);     // segsum out lo
    float* z2 = (float*)alloc((size_t)MPAD * HD * 4);   // gin_mlp out (fp32)
    u16* w1hi = (u16*)alloc((size_t)NL * 32768 * 2);
    u16* w1lo = (u16*)alloc((size_t)NL * 32768 * 2);
    u16* w2hi = (u16*)alloc((size_t)NL * 32768 * 2);
    u16* w2lo = (u16*)alloc((size_t)NL * 32768 * 2);
    float* P = (float*)alloc(17 * HD * 4);
    float* sums = (float*)alloc(256 * 4);
    float* scale = (float*)alloc(HD * 4);
    float* shift = (float*)alloc(HD * 4);
    float* emb = (float*)alloc((size_t)NG * 384 * 4);
    float* psum = (float*)alloc((size_t)NG * PCH * HD * 4);
    float* pmax = (float*)alloc((size_t)NG * PCH * HD * 4);
    int* deg = (int*)alloc((size_t)NN * 4);
    int* rowstart = (int*)alloc((size_t)(NN + 1) * 4);
    int* rank = (int*)alloc((size_t)NE * 4);
    int* csr_src = (int*)alloc((size_t)NE * 4);
    int* partials = (int*)alloc(64 * 4);

    // embedding + projection + weight prep
    proj_tables_kernel<<<1, 128, 0, stream>>>(node_emb, comp_emb, pin_emb, proj_w, P);
    embed_kernel<<<(NN * 32 + 255) / 256, 256, 0, stream>>>(x, P, proj_b, h, hb);
    prep_weights_kernel<<<(NL * 32768 + 255) / 256, 256, 0, stream>>>(gin_w1, gin_w2,
                                                                      w1hi, w1lo, w2hi, w2lo);

    // CSR build (once per call; atomics only in hist, ranks recorded)
    hipMemsetAsync(deg, 0, (size_t)NN * 4, stream);
    hist_kernel<<<(NE + 255) / 256, 256, 0, stream>>>(edst, deg, rank);
    int nblk = (NN + 2047) / 2048;  // 49
    scan1_kernel<<<nblk, 256, 0, stream>>>(deg, rowstart, partials);
    scan2_kernel<<<1, 64, 0, stream>>>(partials, rowstart, nblk);
    scan3_kernel<<<(NN + 255) / 256, 256, 0, stream>>>(rowstart, partials);
    fill_kernel<<<(NE + 255) / 256, 256, 0, stream>>>(esrc, edst, rowstart, rank, csr_src);

    const int gm = MPAD / 64;  // 1564
    for (int l = 0; l < NL; ++l) {
        segsum_kernel<<<(NN * 64 + 255) / 256, 256, 0, stream>>>(h, hb, rowstart, csr_src, z_hi, z_lo);
        hipMemsetAsync(sums, 0, 256 * 4, stream);
        gin_mlp<<<gm, 256, 0, stream>>>(z_hi, z_lo,
                                        w1hi + (size_t)l * 32768, w1lo + (size_t)l * 32768,
                                        w2hi + (size_t)l * 32768, w2lo + (size_t)l * 32768,
                                        gin_b1 + (size_t)l * 256, gin_b2 + (size_t)l * HD,
                                        z2, sums);
        bn_finalize_kernel<<<1, 128, 0, stream>>>(sums, bn_gamma + l * HD, bn_beta + l * HD, scale, shift);
        bn_apply_kernel<<<(NN * 32 + 255) / 256, 256, 0, stream>>>(z2, scale, shift, h, hb, l > 0 ? 1 : 0);
    }

    pool_part_kernel<<<dim3(NG, PCH), 256, 0, stream>>>(h, batch, psum, pmax);
    pool_combine_kernel<<<NG, 128, 0, stream>>>(psum, pmax, batch, emb);
    head_kernel<<<NG, 256, 0, stream>>>(emb, fus_w1, fus_b1, fus_w2, fus_b2, cls_w, cls_b,
                                        (float*)d_out);
}